// Round 5
// baseline (847.256 us; speedup 1.0000x reference)
//
#include <hip/hip_runtime.h>

#define HDIM 128
#define GCOUNT 64

// ---- bf16 helpers (manual, RNE) ----
__device__ __forceinline__ float bfl(unsigned u) { return __uint_as_float(u << 16); }
__device__ __forceinline__ float bfh(unsigned u) { return __uint_as_float(u & 0xffff0000u); }
__device__ __forceinline__ unsigned short f2bf(float f) {
  unsigned u = __float_as_uint(f);
  unsigned r = (u + 0x7fffu + ((u >> 16) & 1u)) >> 16;
  return (unsigned short)r;
}
__device__ __forceinline__ unsigned pk2(float a, float b) {
  return (unsigned)f2bf(a) | ((unsigned)f2bf(b) << 16);
}

typedef __attribute__((ext_vector_type(8))) short short8;
typedef __attribute__((ext_vector_type(4))) float f32x4;

// ---------------- setup: zero cnt + transpose 3 weights to bf16 hi/lo ----------------

__global__ void setup_kernel(const float* __restrict__ W0, const float* __restrict__ W1,
                             const float* __restrict__ W2,
                             unsigned short* __restrict__ h0, unsigned short* __restrict__ l0,
                             unsigned short* __restrict__ h1, unsigned short* __restrict__ l1,
                             unsigned short* __restrict__ h2, unsigned short* __restrict__ l2,
                             int* __restrict__ cnt, int n) {
  int b = blockIdx.x, t = threadIdx.x;
  if (b < 192) {
    int w = b >> 6;
    int idx = (b & 63) * 256 + t;
    const float* W = (w == 0) ? W0 : (w == 1) ? W1 : W2;
    unsigned short* hi = (w == 0) ? h0 : (w == 1) ? h1 : h2;
    unsigned short* lo = (w == 0) ? l0 : (w == 1) ? l1 : l2;
    int k = idx >> 7, nn = idx & 127;
    float wv = W[idx];
    unsigned short h = f2bf(wv);
    float hf = __uint_as_float((unsigned)h << 16);
    unsigned short l = f2bf(wv - hf);
    hi[nn * 128 + k] = h;
    lo[nn * 128 + k] = l;
  } else {
    int i = (b - 192) * 256 + t;
    if (i < n) cnt[i] = 0;
  }
}

// ---------------- degree histogram: atomic return value = stable rank ----------------

__global__ void hist_kernel(const int* __restrict__ dst, int* __restrict__ cnt,
                            int* __restrict__ rank, int E) {
  int i0 = blockIdx.x * 2048 + threadIdx.x;
  #pragma unroll
  for (int j = 0; j < 8; j++) {
    int e = i0 + j * 256;
    if (e < E) rank[e] = atomicAdd(&cnt[dst[e]], 1);
  }
}

// ---------------- scan1: per-block exclusive scan of cnt + dinv ----------------

__global__ void scan1(const int* __restrict__ cnt, int* __restrict__ row_ptr,
                      int* __restrict__ bsum, float* __restrict__ dinv, int n) {
  __shared__ int sh[256];
  int t = threadIdx.x;
  int i = blockIdx.x * 256 + t;
  int v = (i < n) ? cnt[i] : 0;
  if (i < n) dinv[i] = rsqrtf((float)v + 1.0f);
  sh[t] = v;
  __syncthreads();
  for (int off = 1; off < 256; off <<= 1) {
    int u = (t >= off) ? sh[t - off] : 0;
    __syncthreads();
    sh[t] += u;
    __syncthreads();
  }
  if (i < n) row_ptr[i] = sh[t] - v;
  if (t == 255) bsum[blockIdx.x] = sh[255];
}

// ---------------- scan23: each block redundantly scans bsum, applies offset ----------
// 512 threads, 1024 rowp elements per block. Requires nb <= 512.

__global__ void scan23(int* __restrict__ rowp, const int* __restrict__ bsum,
                       int nb, int n, int E) {
  __shared__ int sh[512];
  int t = threadIdx.x;
  sh[t] = (t < nb) ? bsum[t] : 0;
  __syncthreads();
  for (int off = 1; off < 512; off <<= 1) {
    int u = (t >= off) ? sh[t - off] : 0;
    __syncthreads();
    sh[t] += u;
    __syncthreads();
  }
  #pragma unroll
  for (int k = 0; k < 2; k++) {
    int i = blockIdx.x * 1024 + k * 512 + t;
    if (i < n) {
      int j = i >> 8;
      int add = j ? sh[j - 1] : 0;
      rowp[i] += add;
    }
  }
  if (blockIdx.x == 0 && t == 0) rowp[n] = E;
}

// ---------------- fill (atomic-free scatter) + prescale, one dispatch ----------------

__global__ void fill_prescale(const int* __restrict__ src, const int* __restrict__ dst,
                              const int* __restrict__ rank, const int* __restrict__ rowp,
                              int* __restrict__ col, int E,
                              const float* __restrict__ x, const float* __restrict__ dinv,
                              unsigned short* __restrict__ S, int n4, int fb) {
  int b = blockIdx.x, t = threadIdx.x;
  if (b < fb) {
    int i0 = b * 2048 + t;
    #pragma unroll
    for (int j = 0; j < 8; j++) {
      int e = i0 + j * 256;
      if (e < E) col[rowp[dst[e]] + rank[e]] = src[e];
    }
  } else {
    int i = (b - fb) * 256 + t;
    if (i < n4) {
      float4 v = ((const float4*)x)[i];
      float d = dinv[i >> 5];
      ushort4 o;
      o.x = f2bf(v.x * d); o.y = f2bf(v.y * d); o.z = f2bf(v.z * d); o.w = f2bf(v.w * d);
      ((ushort4*)S)[i] = o;
    }
  }
}

// ---------------- fused agg + MFMA GEMM ----------------
// Block = 64 dst rows, 256 threads. Phase 1: 16-lane groups aggregate rows
// (gather S rows, f32 accumulate, *dinv, pack bf16) into LDS A-tile (stride 272B).
// Phase 2: 4 waves, wave = 16 rows x 128 cols MFMA vs WT hi+lo; relu+bias epilogue.

__global__ __launch_bounds__(256) void agg_gemm(
    const uint4* __restrict__ S, const float* __restrict__ dinv,
    const int* __restrict__ rowp, const int* __restrict__ col,
    const uint4* __restrict__ WThi, const uint4* __restrict__ WTlo,
    const float* __restrict__ bias, int do_scale,
    unsigned short* __restrict__ Y, int n) {
  __shared__ uint4 At[64 * 17];   // 64 rows x 16 uint4, stride 17 (272 B)
  int t = threadIdx.x;
  int group = t >> 4, lane16 = t & 15;
  int block0 = blockIdx.x * 64;

  // ---- phase 1: aggregate 64 rows into LDS ----
  #pragma unroll
  for (int rr = 0; rr < 4; rr++) {
    int r = rr * 16 + group;
    int g = block0 + r;
    uint4 o = make_uint4(0, 0, 0, 0);
    if (g < n) {
      uint4 u = S[(size_t)g * 16 + lane16];
      float a0 = bfl(u.x), a1 = bfh(u.x), a2 = bfl(u.y), a3 = bfh(u.y);
      float a4 = bfl(u.z), a5 = bfh(u.z), a6 = bfl(u.w), a7 = bfh(u.w);
      int e0 = rowp[g], e1 = rowp[g + 1];
      int e = e0;
      for (; e + 1 < e1; e += 2) {
        int s0 = col[e], s1 = col[e + 1];
        uint4 v0 = S[(size_t)s0 * 16 + lane16];
        uint4 v1 = S[(size_t)s1 * 16 + lane16];
        a0 += bfl(v0.x); a1 += bfh(v0.x); a2 += bfl(v0.y); a3 += bfh(v0.y);
        a4 += bfl(v0.z); a5 += bfh(v0.z); a6 += bfl(v0.w); a7 += bfh(v0.w);
        a0 += bfl(v1.x); a1 += bfh(v1.x); a2 += bfl(v1.y); a3 += bfh(v1.y);
        a4 += bfl(v1.z); a5 += bfh(v1.z); a6 += bfl(v1.w); a7 += bfh(v1.w);
      }
      if (e < e1) {
        int s0 = col[e];
        uint4 v0 = S[(size_t)s0 * 16 + lane16];
        a0 += bfl(v0.x); a1 += bfh(v0.x); a2 += bfl(v0.y); a3 += bfh(v0.y);
        a4 += bfl(v0.z); a5 += bfh(v0.z); a6 += bfl(v0.w); a7 += bfh(v0.w);
      }
      float d = dinv[g];
      o.x = pk2(a0 * d, a1 * d); o.y = pk2(a2 * d, a3 * d);
      o.z = pk2(a4 * d, a5 * d); o.w = pk2(a6 * d, a7 * d);
    }
    At[r * 17 + lane16] = o;
  }
  __syncthreads();

  // ---- phase 2: MFMA GEMM, A from LDS ----
  int lane = t & 63, wv = t >> 6;
  int m = lane & 15, quad = lane >> 4;
  int row0 = block0 + wv * 16;
  f32x4 acc[8];
  #pragma unroll
  for (int i = 0; i < 8; i++) acc[i] = (f32x4){0.f, 0.f, 0.f, 0.f};
  #pragma unroll
  for (int kb = 0; kb < 4; kb++) {
    uint4 av = At[(wv * 16 + m) * 17 + kb * 4 + quad];
    short8 af = __builtin_bit_cast(short8, av);
    #pragma unroll
    for (int nt = 0; nt < 8; nt++) {
      int colr = nt * 16 + m;
      uint4 bh = WThi[(size_t)colr * 16 + kb * 4 + quad];
      uint4 bl = WTlo[(size_t)colr * 16 + kb * 4 + quad];
      acc[nt] = __builtin_amdgcn_mfma_f32_16x16x32_bf16(af, __builtin_bit_cast(short8, bh), acc[nt], 0, 0, 0);
      acc[nt] = __builtin_amdgcn_mfma_f32_16x16x32_bf16(af, __builtin_bit_cast(short8, bl), acc[nt], 0, 0, 0);
    }
  }
  #pragma unroll
  for (int r = 0; r < 4; r++) {
    int grow = row0 + quad * 4 + r;
    if (grow < n) {
      float sc = do_scale ? dinv[grow] : 1.0f;
      #pragma unroll
      for (int nt = 0; nt < 8; nt++) {
        int colr = nt * 16 + m;
        float v = fmaxf(acc[nt][r] + bias[colr], 0.f) * sc;
        Y[(size_t)grow * 128 + colr] = f2bf(v);
      }
    }
  }
}

// ---------------- fused mean-pool + classifier: one block per graph ----------------
// batch is sorted; block g binary-searches its [lo,hi) node range, sums rows,
// then computes relu(p@(Wc1top+Wc1bot)+bc1)@Wc2+bc2 entirely in-block.

__global__ void poolcls_kernel(const unsigned short* __restrict__ X,
                               const int* __restrict__ batch, int n,
                               const float* __restrict__ Wc1, const float* __restrict__ bc1,
                               const float* __restrict__ Wc2, const float* __restrict__ bc2,
                               float* __restrict__ out) {
  __shared__ float p[HDIM];
  __shared__ float r0s[HDIM], r1s[HDIM];
  int g = blockIdx.x, t = threadIdx.x;   // 128 threads = columns
  int lo, hi;
  { int a = 0, b = n; while (a < b) { int mid = (a + b) >> 1; if (batch[mid] < g) a = mid + 1; else b = mid; } lo = a; }
  { int a = 0, b = n; while (a < b) { int mid = (a + b) >> 1; if (batch[mid] < g + 1) a = mid + 1; else b = mid; } hi = a; }
  float acc = 0.f;
  int r = lo;
  for (; r + 1 < hi; r += 2) {
    acc += __uint_as_float((unsigned)X[(size_t)r * HDIM + t] << 16);
    acc += __uint_as_float((unsigned)X[(size_t)(r + 1) * HDIM + t] << 16);
  }
  if (r < hi) acc += __uint_as_float((unsigned)X[(size_t)r * HDIM + t] << 16);
  float c = fmaxf((float)(hi - lo), 1.0f);
  p[t] = acc / c;
  __syncthreads();
  float a2 = bc1[t];
  for (int k = 0; k < HDIM; k++) {
    a2 += p[k] * (Wc1[k * HDIM + t] + Wc1[(HDIM + k) * HDIM + t]);
  }
  float h = fmaxf(a2, 0.f);
  r0s[t] = h * Wc2[t * 2 + 0];
  r1s[t] = h * Wc2[t * 2 + 1];
  __syncthreads();
  for (int s2 = 64; s2 > 0; s2 >>= 1) {
    if (t < s2) { r0s[t] += r0s[t + s2]; r1s[t] += r1s[t + s2]; }
    __syncthreads();
  }
  if (t == 0) {
    out[g * 2 + 0] = r0s[0] + bc2[0];
    out[g * 2 + 1] = r1s[0] + bc2[1];
  }
}

// ---------------- launch ----------------

extern "C" void kernel_launch(void* const* d_in, const int* in_sizes, int n_in,
                              void* d_out, int out_size, void* d_ws, size_t ws_size,
                              hipStream_t stream) {
  const float* x   = (const float*)d_in[0];
  const int*   ei  = (const int*)d_in[1];
  const int*   bat = (const int*)d_in[2];
  const float* W0  = (const float*)d_in[3];
  const float* b0  = (const float*)d_in[4];
  const float* W1  = (const float*)d_in[5];
  const float* b1  = (const float*)d_in[6];
  const float* W2  = (const float*)d_in[7];
  const float* b2  = (const float*)d_in[8];
  const float* Wc1 = (const float*)d_in[9];
  const float* bc1 = (const float*)d_in[10];
  const float* Wc2 = (const float*)d_in[11];
  const float* bc2 = (const float*)d_in[12];
  float* out = (float*)d_out;

  int N = in_sizes[0] / HDIM;
  int E = in_sizes[1] / 2;
  const int* src = ei;
  const int* dst = ei + E;

  char* ws = (char*)d_ws;
  size_t off = 0;
  auto alloc = [&](size_t bytes) -> void* {
    void* p = (void*)(ws + off);
    off += (bytes + 511) & ~(size_t)511;
    return p;
  };
  unsigned short* buf0 = (unsigned short*)alloc((size_t)N * HDIM * 2);
  unsigned short* buf1 = (unsigned short*)alloc((size_t)N * HDIM * 2);
  float* dinv = (float*)alloc((size_t)N * 4);
  int*   cnt  = (int*)alloc((size_t)N * 4);
  int*   rowp = (int*)alloc((size_t)(N + 1) * 4);
  int*   col  = (int*)alloc((size_t)E * 4);
  int*   rank = (int*)alloc((size_t)E * 4);
  unsigned short* wt_hi[3], *wt_lo[3];
  for (int i = 0; i < 3; i++) {
    wt_hi[i] = (unsigned short*)alloc(HDIM * HDIM * 2);
    wt_lo[i] = (unsigned short*)alloc(HDIM * HDIM * 2);
  }
  int nb = (N + 255) / 256;
  int* bsum = (int*)alloc((size_t)nb * 4);

  // 1. setup: zero cnt + weight transposes
  setup_kernel<<<192 + nb, 256, 0, stream>>>(W0, W1, W2, wt_hi[0], wt_lo[0],
      wt_hi[1], wt_lo[1], wt_hi[2], wt_lo[2], cnt, N);

  // 2. histogram (+rank)
  int eb8 = (E + 2047) / 2048;
  hist_kernel<<<eb8, 256, 0, stream>>>(dst, cnt, rank, E);

  // 3-4. scans (+dinv)
  scan1<<<nb, 256, 0, stream>>>(cnt, rowp, bsum, dinv, N);
  scan23<<<(N + 1023) / 1024, 512, 0, stream>>>(rowp, bsum, nb, N, E);

  // 5. fill CSR + prescale state
  int n4 = N * 32;
  int pb = (n4 + 255) / 256;
  fill_prescale<<<eb8 + pb, 256, 0, stream>>>(src, dst, rank, rowp, col, E,
      x, dinv, buf0, n4, eb8);

  // 6-8. fused agg+gemm, ping-pong buffers
  int gemmBlocks = (N + 63) / 64;
  agg_gemm<<<gemmBlocks, 256, 0, stream>>>((const uint4*)buf0, dinv, rowp, col,
      (const uint4*)wt_hi[0], (const uint4*)wt_lo[0], b0, 1, buf1, N);
  agg_gemm<<<gemmBlocks, 256, 0, stream>>>((const uint4*)buf1, dinv, rowp, col,
      (const uint4*)wt_hi[1], (const uint4*)wt_lo[1], b1, 1, buf0, N);
  agg_gemm<<<gemmBlocks, 256, 0, stream>>>((const uint4*)buf0, dinv, rowp, col,
      (const uint4*)wt_hi[2], (const uint4*)wt_lo[2], b2, 0, buf1, N);

  // 9. fused pool + classifier
  poolcls_kernel<<<GCOUNT, HDIM, 0, stream>>>(buf1, bat, N, Wc1, bc1, Wc2, bc2, out);
}

// Round 6
// 667.763 us; speedup vs baseline: 1.2688x; 1.2688x over previous
//
#include <hip/hip_runtime.h>

#define HDIM 128
#define GCOUNT 64

// ---- bf16 helpers (manual, RNE) ----
__device__ __forceinline__ float bfl(unsigned u) { return __uint_as_float(u << 16); }
__device__ __forceinline__ float bfh(unsigned u) { return __uint_as_float(u & 0xffff0000u); }
__device__ __forceinline__ unsigned short f2bf(float f) {
  unsigned u = __float_as_uint(f);
  unsigned r = (u + 0x7fffu + ((u >> 16) & 1u)) >> 16;
  return (unsigned short)r;
}
__device__ __forceinline__ unsigned pk2(float a, float b) {
  return (unsigned)f2bf(a) | ((unsigned)f2bf(b) << 16);
}

typedef __attribute__((ext_vector_type(8))) short short8;
typedef __attribute__((ext_vector_type(4))) float f32x4;

// ---------------- setup: zero cnt + transpose 3 weights to bf16 hi/lo ----------------

__global__ void setup_kernel(const float* __restrict__ W0, const float* __restrict__ W1,
                             const float* __restrict__ W2,
                             unsigned short* __restrict__ h0, unsigned short* __restrict__ l0,
                             unsigned short* __restrict__ h1, unsigned short* __restrict__ l1,
                             unsigned short* __restrict__ h2, unsigned short* __restrict__ l2,
                             int* __restrict__ cnt, int n) {
  int b = blockIdx.x, t = threadIdx.x;
  if (b < 192) {
    int w = b >> 6;
    int idx = (b & 63) * 256 + t;
    const float* W = (w == 0) ? W0 : (w == 1) ? W1 : W2;
    unsigned short* hi = (w == 0) ? h0 : (w == 1) ? h1 : h2;
    unsigned short* lo = (w == 0) ? l0 : (w == 1) ? l1 : l2;
    int k = idx >> 7, nn = idx & 127;
    float wv = W[idx];
    unsigned short h = f2bf(wv);
    float hf = __uint_as_float((unsigned)h << 16);
    unsigned short l = f2bf(wv - hf);
    hi[nn * 128 + k] = h;
    lo[nn * 128 + k] = l;
  } else {
    int i = (b - 192) * 256 + t;
    if (i < n) cnt[i] = 0;
  }
}

// ---------------- degree histogram: atomic return value = stable rank ----------------

__global__ void hist_kernel(const int* __restrict__ dst, int* __restrict__ cnt,
                            int* __restrict__ rank, int E) {
  int i0 = blockIdx.x * 2048 + threadIdx.x;
  #pragma unroll
  for (int j = 0; j < 8; j++) {
    int e = i0 + j * 256;
    if (e < E) rank[e] = atomicAdd(&cnt[dst[e]], 1);
  }
}

// ---------------- scan1: per-block exclusive scan of cnt + dinv ----------------

__global__ void scan1(const int* __restrict__ cnt, int* __restrict__ row_ptr,
                      int* __restrict__ bsum, float* __restrict__ dinv, int n) {
  __shared__ int sh[256];
  int t = threadIdx.x;
  int i = blockIdx.x * 256 + t;
  int v = (i < n) ? cnt[i] : 0;
  if (i < n) dinv[i] = rsqrtf((float)v + 1.0f);
  sh[t] = v;
  __syncthreads();
  for (int off = 1; off < 256; off <<= 1) {
    int u = (t >= off) ? sh[t - off] : 0;
    __syncthreads();
    sh[t] += u;
    __syncthreads();
  }
  if (i < n) row_ptr[i] = sh[t] - v;
  if (t == 255) bsum[blockIdx.x] = sh[255];
}

// ---------------- scan23: each block redundantly scans bsum, applies offset ----------

__global__ void scan23(int* __restrict__ rowp, const int* __restrict__ bsum,
                       int nb, int n, int E) {
  __shared__ int sh[512];
  int t = threadIdx.x;
  sh[t] = (t < nb) ? bsum[t] : 0;
  __syncthreads();
  for (int off = 1; off < 512; off <<= 1) {
    int u = (t >= off) ? sh[t - off] : 0;
    __syncthreads();
    sh[t] += u;
    __syncthreads();
  }
  #pragma unroll
  for (int k = 0; k < 2; k++) {
    int i = blockIdx.x * 1024 + k * 512 + t;
    if (i < n) {
      int j = i >> 8;
      int add = j ? sh[j - 1] : 0;
      rowp[i] += add;
    }
  }
  if (blockIdx.x == 0 && t == 0) rowp[n] = E;
}

// ---------------- fill (atomic-free scatter) + prescale, one dispatch ----------------

__global__ void fill_prescale(const int* __restrict__ src, const int* __restrict__ dst,
                              const int* __restrict__ rank, const int* __restrict__ rowp,
                              int* __restrict__ col, int E,
                              const float* __restrict__ x, const float* __restrict__ dinv,
                              unsigned short* __restrict__ S, int n4, int fb) {
  int b = blockIdx.x, t = threadIdx.x;
  if (b < fb) {
    int i0 = b * 2048 + t;
    #pragma unroll
    for (int j = 0; j < 8; j++) {
      int e = i0 + j * 256;
      if (e < E) col[rowp[dst[e]] + rank[e]] = src[e];
    }
  } else {
    int i = (b - fb) * 256 + t;
    if (i < n4) {
      float4 v = ((const float4*)x)[i];
      float d = dinv[i >> 5];
      ushort4 o;
      o.x = f2bf(v.x * d); o.y = f2bf(v.y * d); o.z = f2bf(v.z * d); o.w = f2bf(v.w * d);
      ((ushort4*)S)[i] = o;
    }
  }
}

// ---------------- fused agg + MFMA GEMM ----------------

__global__ __launch_bounds__(256) void agg_gemm(
    const uint4* __restrict__ S, const float* __restrict__ dinv,
    const int* __restrict__ rowp, const int* __restrict__ col,
    const uint4* __restrict__ WThi, const uint4* __restrict__ WTlo,
    const float* __restrict__ bias, int do_scale,
    unsigned short* __restrict__ Y, int n) {
  __shared__ uint4 At[64 * 17];   // 64 rows x 16 uint4, stride 17 (272 B)
  int t = threadIdx.x;
  int group = t >> 4, lane16 = t & 15;
  int block0 = blockIdx.x * 64;

  // ---- phase 1: aggregate 64 rows into LDS ----
  #pragma unroll
  for (int rr = 0; rr < 4; rr++) {
    int r = rr * 16 + group;
    int g = block0 + r;
    uint4 o = make_uint4(0, 0, 0, 0);
    if (g < n) {
      uint4 u = S[(size_t)g * 16 + lane16];
      float a0 = bfl(u.x), a1 = bfh(u.x), a2 = bfl(u.y), a3 = bfh(u.y);
      float a4 = bfl(u.z), a5 = bfh(u.z), a6 = bfl(u.w), a7 = bfh(u.w);
      int e0 = rowp[g], e1 = rowp[g + 1];
      int e = e0;
      for (; e + 1 < e1; e += 2) {
        int s0 = col[e], s1 = col[e + 1];
        uint4 v0 = S[(size_t)s0 * 16 + lane16];
        uint4 v1 = S[(size_t)s1 * 16 + lane16];
        a0 += bfl(v0.x); a1 += bfh(v0.x); a2 += bfl(v0.y); a3 += bfh(v0.y);
        a4 += bfl(v0.z); a5 += bfh(v0.z); a6 += bfl(v0.w); a7 += bfh(v0.w);
        a0 += bfl(v1.x); a1 += bfh(v1.x); a2 += bfl(v1.y); a3 += bfh(v1.y);
        a4 += bfl(v1.z); a5 += bfh(v1.z); a6 += bfl(v1.w); a7 += bfh(v1.w);
      }
      if (e < e1) {
        int s0 = col[e];
        uint4 v0 = S[(size_t)s0 * 16 + lane16];
        a0 += bfl(v0.x); a1 += bfh(v0.x); a2 += bfl(v0.y); a3 += bfh(v0.y);
        a4 += bfl(v0.z); a5 += bfh(v0.z); a6 += bfl(v0.w); a7 += bfh(v0.w);
      }
      float d = dinv[g];
      o.x = pk2(a0 * d, a1 * d); o.y = pk2(a2 * d, a3 * d);
      o.z = pk2(a4 * d, a5 * d); o.w = pk2(a6 * d, a7 * d);
    }
    At[r * 17 + lane16] = o;
  }
  __syncthreads();

  // ---- phase 2: MFMA GEMM, A from LDS ----
  int lane = t & 63, wv = t >> 6;
  int m = lane & 15, quad = lane >> 4;
  int row0 = block0 + wv * 16;
  f32x4 acc[8];
  #pragma unroll
  for (int i = 0; i < 8; i++) acc[i] = (f32x4){0.f, 0.f, 0.f, 0.f};
  #pragma unroll
  for (int kb = 0; kb < 4; kb++) {
    uint4 av = At[(wv * 16 + m) * 17 + kb * 4 + quad];
    short8 af = __builtin_bit_cast(short8, av);
    #pragma unroll
    for (int nt = 0; nt < 8; nt++) {
      int colr = nt * 16 + m;
      uint4 bh = WThi[(size_t)colr * 16 + kb * 4 + quad];
      uint4 bl = WTlo[(size_t)colr * 16 + kb * 4 + quad];
      acc[nt] = __builtin_amdgcn_mfma_f32_16x16x32_bf16(af, __builtin_bit_cast(short8, bh), acc[nt], 0, 0, 0);
      acc[nt] = __builtin_amdgcn_mfma_f32_16x16x32_bf16(af, __builtin_bit_cast(short8, bl), acc[nt], 0, 0, 0);
    }
  }
  #pragma unroll
  for (int r = 0; r < 4; r++) {
    int grow = row0 + quad * 4 + r;
    if (grow < n) {
      float sc = do_scale ? dinv[grow] : 1.0f;
      #pragma unroll
      for (int nt = 0; nt < 8; nt++) {
        int colr = nt * 16 + m;
        float v = fmaxf(acc[nt][r] + bias[colr], 0.f) * sc;
        Y[(size_t)grow * 128 + colr] = f2bf(v);
      }
    }
  }
}

// ---------------- mean pool (batch sorted, bf16 input; parallel, round-4 proven) -----

__global__ void pool_kernel(const unsigned short* __restrict__ X, const int* __restrict__ batch,
                            float* __restrict__ pooled, float* __restrict__ gcnt, int n) {
  int t = threadIdx.x;             // 128 threads = columns
  int r0 = blockIdx.x * 64;
  if (r0 >= n) return;
  int r1 = min(r0 + 64, n);
  int g = batch[r0];
  float acc = 0.f, cl = 0.f;
  for (int r = r0; r < r1; r++) {
    int gr = batch[r];
    if (gr != g) {
      atomicAdd(&pooled[g * HDIM + t], acc);
      if (t == 0) atomicAdd(&gcnt[g], cl);
      acc = 0.f; cl = 0.f; g = gr;
    }
    acc += __uint_as_float((unsigned)X[(size_t)r * HDIM + t] << 16);
    cl += 1.f;
  }
  atomicAdd(&pooled[g * HDIM + t], acc);
  if (t == 0) atomicAdd(&gcnt[g], cl);
}

// ---------------- classifier head ----------------

__global__ void cls_kernel(const float* __restrict__ pooled, const float* __restrict__ gcnt,
                           const float* __restrict__ Wc1, const float* __restrict__ bc1,
                           const float* __restrict__ Wc2, const float* __restrict__ bc2,
                           float* __restrict__ out) {
  __shared__ float p[HDIM];
  __shared__ float r0s[HDIM], r1s[HDIM];
  int g = blockIdx.x, t = threadIdx.x;
  float c = fmaxf(gcnt[g], 1.0f);
  p[t] = pooled[g * HDIM + t] / c;
  __syncthreads();
  float acc = bc1[t];
  for (int k = 0; k < HDIM; k++) {
    acc += p[k] * (Wc1[k * HDIM + t] + Wc1[(HDIM + k) * HDIM + t]);
  }
  float h = fmaxf(acc, 0.f);
  r0s[t] = h * Wc2[t * 2 + 0];
  r1s[t] = h * Wc2[t * 2 + 1];
  __syncthreads();
  for (int s2 = 64; s2 > 0; s2 >>= 1) {
    if (t < s2) { r0s[t] += r0s[t + s2]; r1s[t] += r1s[t + s2]; }
    __syncthreads();
  }
  if (t == 0) {
    out[g * 2 + 0] = r0s[0] + bc2[0];
    out[g * 2 + 1] = r1s[0] + bc2[1];
  }
}

// ---------------- launch ----------------

extern "C" void kernel_launch(void* const* d_in, const int* in_sizes, int n_in,
                              void* d_out, int out_size, void* d_ws, size_t ws_size,
                              hipStream_t stream) {
  const float* x   = (const float*)d_in[0];
  const int*   ei  = (const int*)d_in[1];
  const int*   bat = (const int*)d_in[2];
  const float* W0  = (const float*)d_in[3];
  const float* b0  = (const float*)d_in[4];
  const float* W1  = (const float*)d_in[5];
  const float* b1  = (const float*)d_in[6];
  const float* W2  = (const float*)d_in[7];
  const float* b2  = (const float*)d_in[8];
  const float* Wc1 = (const float*)d_in[9];
  const float* bc1 = (const float*)d_in[10];
  const float* Wc2 = (const float*)d_in[11];
  const float* bc2 = (const float*)d_in[12];
  float* out = (float*)d_out;

  int N = in_sizes[0] / HDIM;
  int E = in_sizes[1] / 2;
  const int* src = ei;
  const int* dst = ei + E;

  char* ws = (char*)d_ws;
  size_t off = 0;
  auto alloc = [&](size_t bytes) -> void* {
    void* p = (void*)(ws + off);
    off += (bytes + 511) & ~(size_t)511;
    return p;
  };
  unsigned short* buf0 = (unsigned short*)alloc((size_t)N * HDIM * 2);
  unsigned short* buf1 = (unsigned short*)alloc((size_t)N * HDIM * 2);
  float* dinv = (float*)alloc((size_t)N * 4);
  int*   cnt  = (int*)alloc((size_t)N * 4);
  int*   rowp = (int*)alloc((size_t)(N + 1) * 4);
  int*   col  = (int*)alloc((size_t)E * 4);
  int*   rank = (int*)alloc((size_t)E * 4);
  float* pooled = (float*)alloc((size_t)GCOUNT * HDIM * 4);
  float* gcnt   = (float*)alloc((size_t)GCOUNT * 4);
  unsigned short* wt_hi[3], *wt_lo[3];
  for (int i = 0; i < 3; i++) {
    wt_hi[i] = (unsigned short*)alloc(HDIM * HDIM * 2);
    wt_lo[i] = (unsigned short*)alloc(HDIM * HDIM * 2);
  }
  int nb = (N + 255) / 256;
  int* bsum = (int*)alloc((size_t)nb * 4);

  hipMemsetAsync(pooled, 0, (size_t)GCOUNT * HDIM * 4, stream);
  hipMemsetAsync(gcnt, 0, (size_t)GCOUNT * 4, stream);

  // 1. setup: zero cnt + weight transposes
  setup_kernel<<<192 + nb, 256, 0, stream>>>(W0, W1, W2, wt_hi[0], wt_lo[0],
      wt_hi[1], wt_lo[1], wt_hi[2], wt_lo[2], cnt, N);

  // 2. histogram (+rank)
  int eb8 = (E + 2047) / 2048;
  hist_kernel<<<eb8, 256, 0, stream>>>(dst, cnt, rank, E);

  // 3-4. scans (+dinv)
  scan1<<<nb, 256, 0, stream>>>(cnt, rowp, bsum, dinv, N);
  scan23<<<(N + 1023) / 1024, 512, 0, stream>>>(rowp, bsum, nb, N, E);

  // 5. fill CSR + prescale state
  int n4 = N * 32;
  int pb = (n4 + 255) / 256;
  fill_prescale<<<eb8 + pb, 256, 0, stream>>>(src, dst, rank, rowp, col, E,
      x, dinv, buf0, n4, eb8);

  // 6-8. fused agg+gemm, ping-pong buffers
  int gemmBlocks = (N + 63) / 64;
  agg_gemm<<<gemmBlocks, 256, 0, stream>>>((const uint4*)buf0, dinv, rowp, col,
      (const uint4*)wt_hi[0], (const uint4*)wt_lo[0], b0, 1, buf1, N);
  agg_gemm<<<gemmBlocks, 256, 0, stream>>>((const uint4*)buf1, dinv, rowp, col,
      (const uint4*)wt_hi[1], (const uint4*)wt_lo[1], b1, 1, buf0, N);
  agg_gemm<<<gemmBlocks, 256, 0, stream>>>((const uint4*)buf0, dinv, rowp, col,
      (const uint4*)wt_hi[2], (const uint4*)wt_lo[2], b2, 0, buf1, N);

  // 9-10. parallel pool + classifier
  pool_kernel<<<(N + 63) / 64, 128, 0, stream>>>(buf1, bat, pooled, gcnt, N);
  cls_kernel<<<GCOUNT, HDIM, 0, stream>>>(pooled, gcnt, Wc1, bc1, Wc2, bc2, out);
}

// Round 7
// 622.301 us; speedup vs baseline: 1.3615x; 1.0731x over previous
//
#include <hip/hip_runtime.h>

#define HDIM 128
#define GCOUNT 64

// ---- bf16 helpers (manual, RNE) ----
__device__ __forceinline__ float bfl(unsigned u) { return __uint_as_float(u << 16); }
__device__ __forceinline__ float bfh(unsigned u) { return __uint_as_float(u & 0xffff0000u); }
__device__ __forceinline__ unsigned short f2bf(float f) {
  unsigned u = __float_as_uint(f);
  unsigned r = (u + 0x7fffu + ((u >> 16) & 1u)) >> 16;
  return (unsigned short)r;
}
__device__ __forceinline__ unsigned pk2(float a, float b) {
  return (unsigned)f2bf(a) | ((unsigned)f2bf(b) << 16);
}

typedef __attribute__((ext_vector_type(8))) short short8;
typedef __attribute__((ext_vector_type(4))) float f32x4;

// ---------------- setup: zero cnt + transpose 3 weights to bf16 hi/lo ----------------

__global__ void setup_kernel(const float* __restrict__ W0, const float* __restrict__ W1,
                             const float* __restrict__ W2,
                             unsigned short* __restrict__ h0, unsigned short* __restrict__ l0,
                             unsigned short* __restrict__ h1, unsigned short* __restrict__ l1,
                             unsigned short* __restrict__ h2, unsigned short* __restrict__ l2,
                             int* __restrict__ cnt, int n) {
  int b = blockIdx.x, t = threadIdx.x;
  if (b < 192) {
    int w = b >> 6;
    int idx = (b & 63) * 256 + t;
    const float* W = (w == 0) ? W0 : (w == 1) ? W1 : W2;
    unsigned short* hi = (w == 0) ? h0 : (w == 1) ? h1 : h2;
    unsigned short* lo = (w == 0) ? l0 : (w == 1) ? l1 : l2;
    int k = idx >> 7, nn = idx & 127;
    float wv = W[idx];
    unsigned short h = f2bf(wv);
    float hf = __uint_as_float((unsigned)h << 16);
    unsigned short l = f2bf(wv - hf);
    hi[nn * 128 + k] = h;
    lo[nn * 128 + k] = l;
  } else {
    int i = (b - 192) * 256 + t;
    if (i < n) cnt[i] = 0;
  }
}

// ---------------- degree histogram: atomic return value = stable rank ----------------

__global__ void hist_kernel(const int* __restrict__ dst, int* __restrict__ cnt,
                            int* __restrict__ rank, int E) {
  int i0 = blockIdx.x * 2048 + threadIdx.x;
  #pragma unroll
  for (int j = 0; j < 8; j++) {
    int e = i0 + j * 256;
    if (e < E) rank[e] = atomicAdd(&cnt[dst[e]], 1);
  }
}

// ---------------- scan1: per-block exclusive scan of cnt + dinv ----------------

__global__ void scan1(const int* __restrict__ cnt, int* __restrict__ row_ptr,
                      int* __restrict__ bsum, float* __restrict__ dinv, int n) {
  __shared__ int sh[256];
  int t = threadIdx.x;
  int i = blockIdx.x * 256 + t;
  int v = (i < n) ? cnt[i] : 0;
  if (i < n) dinv[i] = rsqrtf((float)v + 1.0f);
  sh[t] = v;
  __syncthreads();
  for (int off = 1; off < 256; off <<= 1) {
    int u = (t >= off) ? sh[t - off] : 0;
    __syncthreads();
    sh[t] += u;
    __syncthreads();
  }
  if (i < n) row_ptr[i] = sh[t] - v;
  if (t == 255) bsum[blockIdx.x] = sh[255];
}

// ---------------- scan23: each block redundantly scans bsum, applies offset ----------

__global__ void scan23(int* __restrict__ rowp, const int* __restrict__ bsum,
                       int nb, int n, int E) {
  __shared__ int sh[512];
  int t = threadIdx.x;
  sh[t] = (t < nb) ? bsum[t] : 0;
  __syncthreads();
  for (int off = 1; off < 512; off <<= 1) {
    int u = (t >= off) ? sh[t - off] : 0;
    __syncthreads();
    sh[t] += u;
    __syncthreads();
  }
  #pragma unroll
  for (int k = 0; k < 2; k++) {
    int i = blockIdx.x * 1024 + k * 512 + t;
    if (i < n) {
      int j = i >> 8;
      int add = j ? sh[j - 1] : 0;
      rowp[i] += add;
    }
  }
  if (blockIdx.x == 0 && t == 0) rowp[n] = E;
}

// ---------------- fill (atomic-free scatter) + prescale, one dispatch ----------------

__global__ void fill_prescale(const int* __restrict__ src, const int* __restrict__ dst,
                              const int* __restrict__ rank, const int* __restrict__ rowp,
                              int* __restrict__ col, int E,
                              const float* __restrict__ x, const float* __restrict__ dinv,
                              unsigned short* __restrict__ S, int n4, int fb) {
  int b = blockIdx.x, t = threadIdx.x;
  if (b < fb) {
    int i0 = b * 2048 + t;
    #pragma unroll
    for (int j = 0; j < 8; j++) {
      int e = i0 + j * 256;
      if (e < E) col[rowp[dst[e]] + rank[e]] = src[e];
    }
  } else {
    int i = (b - fb) * 256 + t;
    if (i < n4) {
      float4 v = ((const float4*)x)[i];
      float d = dinv[i >> 5];
      ushort4 o;
      o.x = f2bf(v.x * d); o.y = f2bf(v.y * d); o.z = f2bf(v.z * d); o.w = f2bf(v.w * d);
      ((ushort4*)S)[i] = o;
    }
  }
}

// ---------------- aggregation (scaled bf16 state; light & max-parallel) --------------
// One 16-lane group per dst row; 4-way unrolled edge loop for MLP.

__global__ void agg_bf16(const uint4* __restrict__ S, const float* __restrict__ dinv,
                         const int* __restrict__ rowp, const int* __restrict__ col,
                         uint4* __restrict__ OUT, int n) {
  int g = (blockIdx.x * blockDim.x + threadIdx.x) >> 4;
  int lane = threadIdx.x & 15;
  if (g >= n) return;
  uint4 u = S[(size_t)g * 16 + lane];
  float a0 = bfl(u.x), a1 = bfh(u.x), a2 = bfl(u.y), a3 = bfh(u.y);
  float a4 = bfl(u.z), a5 = bfh(u.z), a6 = bfl(u.w), a7 = bfh(u.w);
  int e0 = rowp[g], e1 = rowp[g + 1];
  int e = e0;
  for (; e + 3 < e1; e += 4) {
    int s0 = col[e], s1 = col[e + 1], s2 = col[e + 2], s3 = col[e + 3];
    uint4 v0 = S[(size_t)s0 * 16 + lane];
    uint4 v1 = S[(size_t)s1 * 16 + lane];
    uint4 v2 = S[(size_t)s2 * 16 + lane];
    uint4 v3 = S[(size_t)s3 * 16 + lane];
    a0 += bfl(v0.x); a1 += bfh(v0.x); a2 += bfl(v0.y); a3 += bfh(v0.y);
    a4 += bfl(v0.z); a5 += bfh(v0.z); a6 += bfl(v0.w); a7 += bfh(v0.w);
    a0 += bfl(v1.x); a1 += bfh(v1.x); a2 += bfl(v1.y); a3 += bfh(v1.y);
    a4 += bfl(v1.z); a5 += bfh(v1.z); a6 += bfl(v1.w); a7 += bfh(v1.w);
    a0 += bfl(v2.x); a1 += bfh(v2.x); a2 += bfl(v2.y); a3 += bfh(v2.y);
    a4 += bfl(v2.z); a5 += bfh(v2.z); a6 += bfl(v2.w); a7 += bfh(v2.w);
    a0 += bfl(v3.x); a1 += bfh(v3.x); a2 += bfl(v3.y); a3 += bfh(v3.y);
    a4 += bfl(v3.z); a5 += bfh(v3.z); a6 += bfl(v3.w); a7 += bfh(v3.w);
  }
  for (; e < e1; e++) {
    int s = col[e];
    uint4 v = S[(size_t)s * 16 + lane];
    a0 += bfl(v.x); a1 += bfh(v.x); a2 += bfl(v.y); a3 += bfh(v.y);
    a4 += bfl(v.z); a5 += bfh(v.z); a6 += bfl(v.w); a7 += bfh(v.w);
  }
  float d = dinv[g];
  uint4 o;
  o.x = pk2(a0 * d, a1 * d); o.y = pk2(a2 * d, a3 * d);
  o.z = pk2(a4 * d, a5 * d); o.w = pk2(a6 * d, a7 * d);
  OUT[(size_t)g * 16 + lane] = o;
}

// ---------------- MFMA GEMM: Y = relu(A @ W + b) [* dinv], A bf16 [n,128] ------------

__global__ __launch_bounds__(256) void gemm_mfma(
    const uint4* __restrict__ A, const uint4* __restrict__ WThi, const uint4* __restrict__ WTlo,
    const float* __restrict__ bias, const float* __restrict__ dinv, int do_scale,
    unsigned short* __restrict__ Y, int n) {
  int t = threadIdx.x;
  int lane = t & 63, wv = t >> 6;
  int m = lane & 15, quad = lane >> 4;
  int row0 = blockIdx.x * 64 + wv * 16;
  int arow = row0 + m;
  f32x4 acc[8];
  #pragma unroll
  for (int i = 0; i < 8; i++) acc[i] = (f32x4){0.f, 0.f, 0.f, 0.f};
  #pragma unroll
  for (int kb = 0; kb < 4; kb++) {
    uint4 av = (arow < n) ? A[(size_t)arow * 16 + kb * 4 + quad] : make_uint4(0, 0, 0, 0);
    short8 af = __builtin_bit_cast(short8, av);
    #pragma unroll
    for (int nt = 0; nt < 8; nt++) {
      int colr = nt * 16 + m;
      uint4 bh = WThi[(size_t)colr * 16 + kb * 4 + quad];
      uint4 bl = WTlo[(size_t)colr * 16 + kb * 4 + quad];
      acc[nt] = __builtin_amdgcn_mfma_f32_16x16x32_bf16(af, __builtin_bit_cast(short8, bh), acc[nt], 0, 0, 0);
      acc[nt] = __builtin_amdgcn_mfma_f32_16x16x32_bf16(af, __builtin_bit_cast(short8, bl), acc[nt], 0, 0, 0);
    }
  }
  #pragma unroll
  for (int r = 0; r < 4; r++) {
    int grow = row0 + quad * 4 + r;
    if (grow < n) {
      float sc = do_scale ? dinv[grow] : 1.0f;
      #pragma unroll
      for (int nt = 0; nt < 8; nt++) {
        int colr = nt * 16 + m;
        float v = fmaxf(acc[nt][r] + bias[colr], 0.f) * sc;
        Y[(size_t)grow * 128 + colr] = f2bf(v);
      }
    }
  }
}

// ---------------- mean pool (batch sorted, bf16 input; parallel) ----------------

__global__ void pool_kernel(const unsigned short* __restrict__ X, const int* __restrict__ batch,
                            float* __restrict__ pooled, float* __restrict__ gcnt, int n) {
  int t = threadIdx.x;             // 128 threads = columns
  int r0 = blockIdx.x * 64;
  if (r0 >= n) return;
  int r1 = min(r0 + 64, n);
  int g = batch[r0];
  float acc = 0.f, cl = 0.f;
  for (int r = r0; r < r1; r++) {
    int gr = batch[r];
    if (gr != g) {
      atomicAdd(&pooled[g * HDIM + t], acc);
      if (t == 0) atomicAdd(&gcnt[g], cl);
      acc = 0.f; cl = 0.f; g = gr;
    }
    acc += __uint_as_float((unsigned)X[(size_t)r * HDIM + t] << 16);
    cl += 1.f;
  }
  atomicAdd(&pooled[g * HDIM + t], acc);
  if (t == 0) atomicAdd(&gcnt[g], cl);
}

// ---------------- classifier head ----------------

__global__ void cls_kernel(const float* __restrict__ pooled, const float* __restrict__ gcnt,
                           const float* __restrict__ Wc1, const float* __restrict__ bc1,
                           const float* __restrict__ Wc2, const float* __restrict__ bc2,
                           float* __restrict__ out) {
  __shared__ float p[HDIM];
  __shared__ float r0s[HDIM], r1s[HDIM];
  int g = blockIdx.x, t = threadIdx.x;
  float c = fmaxf(gcnt[g], 1.0f);
  p[t] = pooled[g * HDIM + t] / c;
  __syncthreads();
  float acc = bc1[t];
  for (int k = 0; k < HDIM; k++) {
    acc += p[k] * (Wc1[k * HDIM + t] + Wc1[(HDIM + k) * HDIM + t]);
  }
  float h = fmaxf(acc, 0.f);
  r0s[t] = h * Wc2[t * 2 + 0];
  r1s[t] = h * Wc2[t * 2 + 1];
  __syncthreads();
  for (int s2 = 64; s2 > 0; s2 >>= 1) {
    if (t < s2) { r0s[t] += r0s[t + s2]; r1s[t] += r1s[t + s2]; }
    __syncthreads();
  }
  if (t == 0) {
    out[g * 2 + 0] = r0s[0] + bc2[0];
    out[g * 2 + 1] = r1s[0] + bc2[1];
  }
}

// ---------------- launch ----------------

extern "C" void kernel_launch(void* const* d_in, const int* in_sizes, int n_in,
                              void* d_out, int out_size, void* d_ws, size_t ws_size,
                              hipStream_t stream) {
  const float* x   = (const float*)d_in[0];
  const int*   ei  = (const int*)d_in[1];
  const int*   bat = (const int*)d_in[2];
  const float* W0  = (const float*)d_in[3];
  const float* b0  = (const float*)d_in[4];
  const float* W1  = (const float*)d_in[5];
  const float* b1  = (const float*)d_in[6];
  const float* W2  = (const float*)d_in[7];
  const float* b2  = (const float*)d_in[8];
  const float* Wc1 = (const float*)d_in[9];
  const float* bc1 = (const float*)d_in[10];
  const float* Wc2 = (const float*)d_in[11];
  const float* bc2 = (const float*)d_in[12];
  float* out = (float*)d_out;

  int N = in_sizes[0] / HDIM;
  int E = in_sizes[1] / 2;
  const int* src = ei;
  const int* dst = ei + E;

  char* ws = (char*)d_ws;
  size_t off = 0;
  auto alloc = [&](size_t bytes) -> void* {
    void* p = (void*)(ws + off);
    off += (bytes + 511) & ~(size_t)511;
    return p;
  };
  unsigned short* buf0 = (unsigned short*)alloc((size_t)N * HDIM * 2);  // state
  unsigned short* buf1 = (unsigned short*)alloc((size_t)N * HDIM * 2);  // agg out
  float* dinv = (float*)alloc((size_t)N * 4);
  int*   cnt  = (int*)alloc((size_t)N * 4);
  int*   rowp = (int*)alloc((size_t)(N + 1) * 4);
  int*   col  = (int*)alloc((size_t)E * 4);
  int*   rank = (int*)alloc((size_t)E * 4);
  float* pooled = (float*)alloc((size_t)GCOUNT * HDIM * 4);
  float* gcnt   = (float*)alloc((size_t)GCOUNT * 4);
  unsigned short* wt_hi[3], *wt_lo[3];
  for (int i = 0; i < 3; i++) {
    wt_hi[i] = (unsigned short*)alloc(HDIM * HDIM * 2);
    wt_lo[i] = (unsigned short*)alloc(HDIM * HDIM * 2);
  }
  int nb = (N + 255) / 256;
  int* bsum = (int*)alloc((size_t)nb * 4);

  hipMemsetAsync(pooled, 0, (size_t)GCOUNT * HDIM * 4, stream);
  hipMemsetAsync(gcnt, 0, (size_t)GCOUNT * 4, stream);

  // 1. setup: zero cnt + weight transposes
  setup_kernel<<<192 + nb, 256, 0, stream>>>(W0, W1, W2, wt_hi[0], wt_lo[0],
      wt_hi[1], wt_lo[1], wt_hi[2], wt_lo[2], cnt, N);

  // 2. histogram (+rank)
  int eb8 = (E + 2047) / 2048;
  hist_kernel<<<eb8, 256, 0, stream>>>(dst, cnt, rank, E);

  // 3-4. scans (+dinv)
  scan1<<<nb, 256, 0, stream>>>(cnt, rowp, bsum, dinv, N);
  scan23<<<(N + 1023) / 1024, 512, 0, stream>>>(rowp, bsum, nb, N, E);

  // 5. fill CSR + prescale state
  int n4 = N * 32;
  int pb = (n4 + 255) / 256;
  fill_prescale<<<eb8 + pb, 256, 0, stream>>>(src, dst, rank, rowp, col, E,
      x, dinv, buf0, n4, eb8);

  // 6-11. agg (light, max-parallel) + MFMA gemm, ping-pong
  int aggBlocks = (int)(((size_t)N * 16 + 255) / 256);
  int gemmBlocks = (N + 63) / 64;

  agg_bf16<<<aggBlocks, 256, 0, stream>>>((const uint4*)buf0, dinv, rowp, col, (uint4*)buf1, N);
  gemm_mfma<<<gemmBlocks, 256, 0, stream>>>((const uint4*)buf1, (const uint4*)wt_hi[0],
      (const uint4*)wt_lo[0], b0, dinv, 1, buf0, N);

  agg_bf16<<<aggBlocks, 256, 0, stream>>>((const uint4*)buf0, dinv, rowp, col, (uint4*)buf1, N);
  gemm_mfma<<<gemmBlocks, 256, 0, stream>>>((const uint4*)buf1, (const uint4*)wt_hi[1],
      (const uint4*)wt_lo[1], b1, dinv, 1, buf0, N);

  agg_bf16<<<aggBlocks, 256, 0, stream>>>((const uint4*)buf0, dinv, rowp, col, (uint4*)buf1, N);
  gemm_mfma<<<gemmBlocks, 256, 0, stream>>>((const uint4*)buf1, (const uint4*)wt_hi[2],
      (const uint4*)wt_lo[2], b2, dinv, 0, buf0, N);

  // 12-13. parallel pool + classifier
  pool_kernel<<<(N + 63) / 64, 128, 0, stream>>>(buf0, bat, pooled, gcnt, N);
  cls_kernel<<<GCOUNT, HDIM, 0, stream>>>(pooled, gcnt, Wc1, bc1, Wc2, bc2, out);
}